// Round 5
// baseline (175.741 us; speedup 1.0000x reference)
//
#include <hip/hip_runtime.h>

typedef short bf16x8 __attribute__((ext_vector_type(8)));
typedef float f32x4 __attribute__((ext_vector_type(4)));
typedef unsigned short us8 __attribute__((ext_vector_type(8)));

__device__ __forceinline__ unsigned short f2bf(float f) {
    unsigned int u = __float_as_uint(f);
    u += 0x7fffu + ((u >> 16) & 1u);   // round-to-nearest-even
    return (unsigned short)(u >> 16);
}

__device__ __forceinline__ void gload16(const void* g, void* l) {
    __builtin_amdgcn_global_load_lds((const __attribute__((address_space(1))) void*)g,
                                     (__attribute__((address_space(3))) void*)l, 16, 0, 0);
}

__device__ __forceinline__ bf16x8 cvt_pk8(float4 a, float4 b) {
    union { bf16x8 h; unsigned int u[4]; } r;
    asm("v_cvt_pk_bf16_f32 %0, %1, %2" : "=v"(r.u[0]) : "v"(a.x), "v"(a.y));
    asm("v_cvt_pk_bf16_f32 %0, %1, %2" : "=v"(r.u[1]) : "v"(a.z), "v"(a.w));
    asm("v_cvt_pk_bf16_f32 %0, %1, %2" : "=v"(r.u[2]) : "v"(b.x), "v"(b.y));
    asm("v_cvt_pk_bf16_f32 %0, %1, %2" : "=v"(r.u[3]) : "v"(b.z), "v"(b.w));
    return r.h;
}

// ---- transpose + cast fp32 -> bf16 bits: out[Cc][R] = cast(in[R][Cc]) ----
__global__ __launch_bounds__(256) void transpose_cast_kernel(
    const float* __restrict__ in, unsigned short* __restrict__ out, int R, int Cc) {
    __shared__ alignas(16) unsigned short sT[64][65];
    const int r0 = blockIdx.x * 64, c0 = blockIdx.y * 64;
    const int t = threadIdx.x;
#pragma unroll
    for (int p = 0; p < 16; ++p) {
        int flat = p * 256 + t;
        int r = flat >> 6, c = flat & 63;
        sT[c][r] = f2bf(in[(size_t)(r0 + r) * Cc + (c0 + c)]);
    }
    __syncthreads();
#pragma unroll
    for (int p = 0; p < 16; ++p) {
        int flat = p * 256 + t;
        int c = flat >> 6, r = flat & 63;
        out[(size_t)(c0 + c) * R + (r0 + r)] = sT[c][r];
    }
}

// ---- small MFMA GEMM (BM=64, 4 waves): C[M][N] = A[M][K] @ (BT[N][K])^T ----
// AMODE 1: A fp32 -> bf16 during staging.
// AMODE 2: A = relu(sum of 4 fp32 slabs, stride aslab) -> bf16 during staging.
// TOUT: write bf16 transposed C[N][M].
template<int BN, int WM, int WN, int AMODE, bool TOUT, typename OutT>
__global__ __launch_bounds__(256) void gemm_kernel(
    const void* __restrict__ Aptr, const unsigned short* __restrict__ BT,
    OutT* __restrict__ C, int M, int N, int K, long aslab) {
    constexpr int BM = 64, BK = 64, LDW = 72;
    constexpr int MF = BM / WM / 16;
    constexpr int NF = BN / WN / 16;
    __shared__ alignas(16) unsigned short sA[BM * LDW];
    __shared__ alignas(16) unsigned short sB[BN * LDW];
    const int t = threadIdx.x;
    const int w = t >> 6, l = t & 63;
    const int wr = w / WN, wc = w % WN;
    const int m0 = blockIdx.x * BM;
    const int klen = K / gridDim.z;
    const int kbeg = blockIdx.z * klen;
    OutT* Cp = C + (size_t)blockIdx.z * M * N;

    f32x4 acc[MF][NF] = {};

    for (int k0 = kbeg; k0 < kbeg + klen; k0 += BK) {
        const float* A32 = (const float*)Aptr;
#pragma unroll
        for (int p = 0; p < 4; ++p) {
            int flat = p * 256 + t;
            int row = flat >> 4, c4 = flat & 15;
            size_t base = (size_t)(m0 + row) * K + k0 + c4 * 4;
            float4 v = *(const float4*)&A32[base];
            if constexpr (AMODE == 2) {
                float4 b = *(const float4*)&A32[aslab + base];
                float4 c = *(const float4*)&A32[2 * aslab + base];
                float4 d = *(const float4*)&A32[3 * aslab + base];
                v.x = fmaxf(v.x + b.x + c.x + d.x, 0.f);
                v.y = fmaxf(v.y + b.y + c.y + d.y, 0.f);
                v.z = fmaxf(v.z + b.z + c.z + d.z, 0.f);
                v.w = fmaxf(v.w + b.w + c.w + d.w, 0.f);
            }
            ushort4 o = make_ushort4(f2bf(v.x), f2bf(v.y), f2bf(v.z), f2bf(v.w));
            *(ushort4*)&sA[row * LDW + c4 * 4] = o;
        }
#pragma unroll
        for (int p = 0; p < BN * 8 / 256; ++p) {
            int flat = p * 256 + t;
            int row = flat >> 3, c8 = flat & 7;
            us8 v = *(const us8*)&BT[(size_t)row * K + k0 + c8 * 8];
            *(us8*)&sB[row * LDW + c8 * 8] = v;
        }
        __syncthreads();
#pragma unroll
        for (int kk = 0; kk < BK; kk += 32) {
            bf16x8 av[MF], bv[NF];
#pragma unroll
            for (int m = 0; m < MF; ++m)
                av[m] = *(const bf16x8*)&sA[(wr * (BM / WM) + m * 16 + (l & 15)) * LDW + kk + (l >> 4) * 8];
#pragma unroll
            for (int n = 0; n < NF; ++n)
                bv[n] = *(const bf16x8*)&sB[(wc * (BN / WN) + n * 16 + (l & 15)) * LDW + kk + (l >> 4) * 8];
#pragma unroll
            for (int m = 0; m < MF; ++m)
#pragma unroll
                for (int n = 0; n < NF; ++n)
                    acc[m][n] = __builtin_amdgcn_mfma_f32_16x16x32_bf16(av[m], bv[n], acc[m][n], 0, 0, 0);
        }
        __syncthreads();
    }

#pragma unroll
    for (int m = 0; m < MF; ++m) {
#pragma unroll
        for (int n = 0; n < NF; ++n) {
            const int col = wc * (BN / WN) + n * 16 + (l & 15);
            const int rb = m0 + wr * (BM / WM) + m * 16 + ((l >> 4) << 2);
            float v0 = acc[m][n][0], v1 = acc[m][n][1], v2 = acc[m][n][2], v3 = acc[m][n][3];
            if constexpr (TOUT) {
                ushort4 o = make_ushort4(f2bf(v0), f2bf(v1), f2bf(v2), f2bf(v3));
                *(ushort4*)((unsigned short*)Cp + (size_t)col * M + rb) = o;
            } else {
                Cp[(size_t)(rb + 0) * N + col] = (OutT)v0;
                Cp[(size_t)(rb + 1) * N + col] = (OutT)v1;
                Cp[(size_t)(rb + 2) * N + col] = (OutT)v2;
                Cp[(size_t)(rb + 3) * N + col] = (OutT)v3;
            }
        }
    }
}

// ---- big adj-streaming GEMM (m97-style): global_load_lds, single-buffer ----
// C (fp32 K-split partials at slab z) = adj[M][K] @ (BT[N][K])^T
// LDS linear; content swizzled via pre-swizzled GLOBAL source (rule #21):
//   A (fp32, 64 f32/row = 16 x 16B units): physical unit p holds logical p^(r&15)
//   B (bf16, 64 bf16/row = 8 x 16B slots): physical slot  s holds logical s^(r&7)
// Read side: phys = logical ^ mask, and since the mask is row-constant, the
// low/high 16B halves of an A fragment keep their order (phys pair = p0, p0^1
// holding logical L0, L0+1) -> unconditional cvt_pk8(fa, fb).
template<int BM, int BN, int WM, int WN, int THREADS>
__global__ __launch_bounds__(THREADS, 4) void big_gemm_kernel(
    const float* __restrict__ A, const unsigned short* __restrict__ BT,
    float* __restrict__ C, int M, int N, int K) {
    constexpr int BK = 64;
    constexpr int NW = THREADS / 64;
    constexpr int MF = BM / WM / 16, NF = BN / WN / 16;
    constexpr int AREG = BM * BK * 4 / 1024;   // 1KB wave-regions of A
    constexpr int BREG = BN * BK * 2 / 1024;   // 1KB wave-regions of B
    __shared__ alignas(16) float sA[BM * BK];
    __shared__ alignas(16) unsigned short sB[BN * BK];
    const int t = threadIdx.x, w = t >> 6, l = t & 63;
    const int wr = w / WN, wc = w % WN;
    const int m0 = blockIdx.x * BM;
    const int klen = K / gridDim.z, kbeg = blockIdx.z * klen;
    const int NT = klen / BK;
    float* Cp = C + (size_t)blockIdx.z * M * N;

    f32x4 acc[MF][NF] = {};

    for (int tt = 0; tt < NT; ++tt) {
        const int k0 = kbeg + tt * BK;
        // stage A: region q = 4 rows of 256B; lane l -> row q*4+(l>>4), phys unit l&15
#pragma unroll
        for (int j = 0; j < AREG / NW; ++j) {
            int q = w + j * NW;
            int r = q * 4 + (l >> 4);
            int col = ((l & 15) ^ (r & 15)) * 4;   // logical unit * 4 f32
            gload16(&A[(size_t)(m0 + r) * K + k0 + col], (char*)sA + q * 1024);
        }
        // stage B: region q = 8 rows of 128B; lane l -> row q*8+(l>>3), phys slot l&7
#pragma unroll
        for (int j = 0; j < BREG / NW; ++j) {
            int q = w + j * NW;
            int r = q * 8 + (l >> 3);
            int col = ((l & 7) ^ (r & 7)) * 8;     // logical slot * 8 bf16
            gload16(&BT[(size_t)r * K + k0 + col], (char*)sB + q * 1024);
        }
        __syncthreads();   // drains vmcnt: LDS tile ready
#pragma unroll
        for (int kk = 0; kk < BK; kk += 32) {
            bf16x8 av[MF], bv[NF];
#pragma unroll
            for (int m = 0; m < MF; ++m) {
                int r = wr * (BM / WM) + m * 16 + (l & 15);
                int p0 = ((kk >> 2) + (l >> 4) * 2) ^ (r & 15);  // phys unit holding logical low half
                float4 fa = *(const float4*)&sA[r * 64 + p0 * 4];
                float4 fb = *(const float4*)&sA[r * 64 + (p0 ^ 1) * 4];
                av[m] = cvt_pk8(fa, fb);   // fa = logical L0, fb = logical L0+1, always
            }
#pragma unroll
            for (int n = 0; n < NF; ++n) {
                int r = wc * (BN / WN) + n * 16 + (l & 15);
                int s = ((kk >> 3) + (l >> 4)) ^ (r & 7);
                bv[n] = *(const bf16x8*)&sB[r * 64 + s * 8];
            }
#pragma unroll
            for (int m = 0; m < MF; ++m)
#pragma unroll
                for (int n = 0; n < NF; ++n)
                    acc[m][n] = __builtin_amdgcn_mfma_f32_16x16x32_bf16(av[m], bv[n], acc[m][n], 0, 0, 0);
        }
        __syncthreads();   // all reads done before next tile's DMA overwrites
    }

#pragma unroll
    for (int m = 0; m < MF; ++m)
#pragma unroll
        for (int n = 0; n < NF; ++n) {
            const int col = wc * (BN / WN) + n * 16 + (l & 15);
            const int rb = m0 + wr * (BM / WM) + m * 16 + ((l >> 4) << 2);
#pragma unroll
            for (int j = 0; j < 4; ++j)
                Cp[(size_t)(rb + j) * N + col] = acc[m][n][j];
        }
}

// ---- head: reduce 8 fp32 partial slabs of o[8192][64], then log_softmax rows ----
__global__ __launch_bounds__(256) void head2_kernel(
    const float* __restrict__ p, float* __restrict__ out, int M) {
    const int t = threadIdx.x, w = t >> 6, l = t & 63;
    const size_t stride = (size_t)M * 64;
#pragma unroll
    for (int rr = 0; rr < 4; ++rr) {
        int i = blockIdx.x * 16 + w * 4 + rr;
        size_t off = (size_t)i * 64 + l;
        float v = 0.f;
#pragma unroll
        for (int s = 0; s < 8; ++s) v += p[s * stride + off];
        float mx = v;
#pragma unroll
        for (int o = 32; o; o >>= 1) mx = fmaxf(mx, __shfl_xor(mx, o));
        float d0 = v - mx;
        float e = __expf(d0);
#pragma unroll
        for (int o = 32; o; o >>= 1) e += __shfl_xor(e, o);
        out[off] = d0 - __logf(e);
    }
}

extern "C" void kernel_launch(void* const* d_in, const int* in_sizes, int n_in,
                              void* d_out, int out_size, void* d_ws, size_t ws_size,
                              hipStream_t stream) {
    const float* adj = (const float*)d_in[0];
    const float* x   = (const float*)d_in[1];
    const float* W1  = (const float*)d_in[2];
    const float* W2  = (const float*)d_in[3];
    float* out = (float*)d_out;

    const int M = 8192, K = 8192;
    char* ws = (char*)d_ws;
    // ws layout (~55.8 MB; ws_size ~1 GB):
    float*          pbuf1 = (float*)ws;                        // 32 MB: 4 slabs t1 partials [8192][256]
    float*          pbuf2 = (float*)(ws + 33554432);           // 16 MB: 8 slabs o partials  [8192][64]
    unsigned short* zT    = (unsigned short*)(ws + 50331648);  //  4 MB: z^T  bf16 [256][8192]
    unsigned short* hwT   = (unsigned short*)(ws + 54525952);  //  1 MB: hw^T bf16 [64][8192]
    unsigned short* W1T   = (unsigned short*)(ws + 55574528);  // 128 KB
    unsigned short* W2T   = (unsigned short*)(ws + 55705600);  // 32 KB

    transpose_cast_kernel<<<dim3(4, 4), 256, 0, stream>>>(W1, W1T, 256, 256);
    transpose_cast_kernel<<<dim3(4, 1), 256, 0, stream>>>(W2, W2T, 256, 64);
    // z^T = (x @ W1)^T, bf16
    gemm_kernel<256, 1, 4, 1, true, unsigned short>
        <<<dim3(M / 64, 1, 1), 256, 0, stream>>>(x, W1T, zT, M, 256, 256, 0);
    // t1 partials = adj @ z  (K-split 4; 512 blocks, 48 KB LDS -> 2-3 blocks/CU)
    big_gemm_kernel<64, 256, 2, 4, 512>
        <<<dim3(M / 64, 1, 4), 512, 0, stream>>>(adj, zT, pbuf1, M, 256, K);
    // hw^T = (relu(sum of 4 t1 slabs) @ W2)^T, bf16
    gemm_kernel<64, 2, 2, 2, true, unsigned short>
        <<<dim3(M / 64, 1, 1), 256, 0, stream>>>(pbuf1, W2T, hwT, M, 64, 256, (long)M * 256);
    // o partials = adj @ hw  (K-split 8; 1024 blocks, 24 KB LDS)
    big_gemm_kernel<64, 64, 4, 2, 512>
        <<<dim3(M / 64, 1, 8), 512, 0, stream>>>(adj, hwT, pbuf2, M, 64, K);
    head2_kernel<<<dim3(M / 16), 256, 0, stream>>>(pbuf2, out, M);
}